// Round 5
// baseline (80.308 us; speedup 1.0000x reference)
//
#include <hip/hip_runtime.h>

// JeffressFilter: T=1024, NC=16 spatial channels, 2 in-features, D_OUT=512 taps.
// out[t,nc,d] = w[d] * ( [t>=dl0]*y[t-dl0, nc, 0] + [t>=dl1]*y[t-dl1, nc, 1] )
// y = leaky-integrator scan of x (decay = exp(-1/2)).
//
// R5: t-major gather. R4's d-major lanes (d-stride 4 floats = 16 B) made every
// strided-tap load span 1 KB / 16 cache lines, x4 un-mergeable base pointers
// -> L1-transaction bound (~26 us). Here lane <-> consecutive d (stride 4 B,
// ~5 lines/instr), thread covers 4 consecutive t for one d (8 scalar loads +
// 4 perfectly-coalesced dword stores per thread). Mask stays free via the
// zero-padded transposed y rows; no LDS, no branches.
//
// ws layout: yA[nc][ROW], yB[nc][ROW]; ROW = 256(zero pad) + 1024(t).

#define T_LEN  1024
#define D_OUT  512
#define NC     16
#define PAD    256
#define ROW    (PAD + T_LEN)    // 1280 floats per row
#define YB_OFF (NC * ROW)       // second feature plane

// ---------------------------------------------------------------------------
// Kernel 1: zero the pads + LIF scan into transposed ws.
// 16 blocks x 64 threads. Block b: all threads zero a slice of the 32 pads;
// threads 0..31 scan chunk b (64 steps) for all 32 channels with a 64-step
// warm-up (truncation ~ exp(-32) = 1.3e-14).
// ---------------------------------------------------------------------------
__global__ __launch_bounds__(64) void lif_scan_kernel(const float* __restrict__ x,
                                                      float* __restrict__ ws) {
    const int tid = threadIdx.x;   // 0..63
    const int b   = blockIdx.x;    // 0..15 == chunk index

    // zero the 32 row-pads (32*256 = 8192 floats; 8 per thread)
    #pragma unroll
    for (int k = 0; k < 8; ++k) {
        const int id = (b * 64 + tid) * 8 + k;   // 0..8191
        const int r  = id >> 8;                  // row 0..31
        const int c  = id & 255;                 // pad col 0..255
        ws[r * ROW + c] = 0.0f;
    }

    if (tid < 32) {
        const int ch = tid;          // nc*2 + i
        const int nc = ch >> 1;
        const int i  = ch & 1;
        float* row = ws + (i ? YB_OFF : 0) + nc * ROW + PAD;

        const int   t0    = b * 64;
        const float decay = 0.60653065971263342f;  // exp(-0.5)

        float v = 0.0f;
        #pragma unroll 8
        for (int k = 0; k < 64; ++k) {
            const int t = t0 - 64 + k;
            const float xv = (t >= 0) ? x[t * 32 + ch] : 0.0f;
            v = decay * v + xv;
        }
        #pragma unroll 8
        for (int k = 0; k < 64; ++k) {
            const int t = t0 + k;
            v = decay * v + x[t * 32 + ch];
            row[t] = v;
        }
    }
}

// ---------------------------------------------------------------------------
// Kernel 2: t-major gather + weight. 8192 blocks x 256 threads.
// Block: nc fixed, d-chunk of 64 (= lane), t-tile of 16 (wave w -> 4 t's).
// Per thread: delay int2 + weight dword (once), 8 scalar gather loads
// (broadcast tap: 1 line/instr; strided tap: lane-stride 4 B, ~5 lines/instr),
// 4 dword stores each 256 B contiguous across the wave.
// ---------------------------------------------------------------------------
__global__ __launch_bounds__(256) void jeffress_kernel(const float* __restrict__ ws,
                                                       const float* __restrict__ w,
                                                       const int* __restrict__ delay,
                                                       float* __restrict__ out) {
    const int bid  = blockIdx.x;
    const int d0   = (bid & 7) * 64;         // d-chunk
    const int nc   = (bid >> 3) & 15;
    const int t0   = (bid >> 7) * 16;        // t-tile
    const int lane = threadIdx.x & 63;
    const int wv   = threadIdx.x >> 6;       // 0..3
    const int d    = d0 + lane;
    const int tb   = t0 + wv * 4;            // first of this thread's 4 t's

    const int2  dl = ((const int2*)delay)[d];
    const float wd = w[d];

    const float* pA = ws + nc * ROW + PAD + tb - dl.x;           // feature 0
    const float* pB = ws + YB_OFF + nc * ROW + PAD + tb - dl.y;  // feature 1

    float* op = out + (size_t)tb * (NC * D_OUT) + nc * D_OUT + d;

    #pragma unroll
    for (int j = 0; j < 4; ++j) {
        op[j * (NC * D_OUT)] = wd * (pA[j] + pB[j]);
    }
}

extern "C" void kernel_launch(void* const* d_in, const int* in_sizes, int n_in,
                              void* d_out, int out_size, void* d_ws, size_t ws_size,
                              hipStream_t stream) {
    const float* x      = (const float*)d_in[0];   // (1024,4,4,2) fp32
    const float* weight = (const float*)d_in[1];   // (512,) fp32
    const int*   delay  = (const int*)d_in[2];     // (512,2) int32
    float* out = (float*)d_out;                    // (1024,4,4,512) fp32
    float* ws  = (float*)d_ws;                     // 40960 floats used

    lif_scan_kernel<<<16, 64, 0, stream>>>(x, ws);

    // 8 d-chunks x 16 nc x 64 t-tiles = 8192 blocks
    jeffress_kernel<<<8192, 256, 0, stream>>>(ws, weight, delay, out);
}